// Round 3
// baseline (3216.130 us; speedup 1.0000x reference)
//
#include <hip/hip_runtime.h>
#include <hip/hip_bf16.h>

#define T 256
#define H 400
#define G4 1600   // 4*H
#define WD 300
#define TD 100
#define MLP_H 400
#define NBLK_D 5      // blocks per direction
#define NPAIR 200     // 400 h values -> 200 packed 64-bit words
#define NPAIRP 208    // padded word count per parity

typedef _Float16 f16;
typedef _Float16 half2t __attribute__((ext_vector_type(2)));
typedef unsigned long long u64;

// ---------- math helpers ----------
__device__ __forceinline__ float fexp(float x) {
    return __builtin_amdgcn_exp2f(x * 1.4426950408889634f);
}
__device__ __forceinline__ float sigf(float x) {
    return __builtin_amdgcn_rcpf(1.0f + fexp(-x));
}
__device__ __forceinline__ float tanhf_fast(float x) {
    return 1.0f - 2.0f * __builtin_amdgcn_rcpf(1.0f + fexp(2.0f * x));
}
__device__ __forceinline__ unsigned short f16bits(f16 x) {
    union { f16 h; unsigned short u; } v; v.h = x; return v.u;
}
__device__ __forceinline__ f16 bits2f16(unsigned short u) {
    union { f16 h; unsigned short u; } v; v.u = u; return v.h;
}

#if __has_builtin(__builtin_amdgcn_fdot2)
__device__ __forceinline__ float dot2f(half2t a, half2t b, float c) {
    return __builtin_amdgcn_fdot2(a, b, c, false);
}
#else
__device__ __forceinline__ float dot2f(half2t a, half2t b, float c) {
    return fmaf((float)a.y, (float)b.y, fmaf((float)a.x, (float)b.x, c));
}
#endif

// ---------- embedding gather ----------
__global__ void gather_k(const int* __restrict__ words, const int* __restrict__ tags,
                         const float* __restrict__ wemb, const float* __restrict__ temb,
                         float* __restrict__ x0) {
    int t = blockIdx.x;
    int w = words[t], g = tags[t];
    for (int c = threadIdx.x; c < H; c += 128) {
        float v = (c < WD) ? wemb[w * WD + c] : temb[g * TD + (c - WD)];
        x0[t * H + c] = v;
    }
}

// ---------- generic GEMM: out[t][r] = sum_k X[t*ldx+k]*W[r*ldw+wofs+k] + bias1[r]+bias2[r]
__global__ __launch_bounds__(256) void gemm_tn(
    const float* __restrict__ X, int ldx,
    const float* __restrict__ Wt, int ldw, int wofs,
    const float* __restrict__ bias1, const float* __restrict__ bias2,
    float* __restrict__ out, int ldo, int Rt, int K) {
    __shared__ float Xs[64][17];
    __shared__ float Ws[64][17];
    const int tid = threadIdx.x;
    const int t0 = blockIdx.x * 64, r0 = blockIdx.y * 64;
    const int lr = tid >> 2, kq = (tid & 3) * 4;
    const int ti = tid >> 4, rj = tid & 15;
    float acc[4][4] = {};
    for (int k0 = 0; k0 < K; k0 += 16) {
        float4 xv = *(const float4*)(X + (size_t)(t0 + lr) * ldx + k0 + kq);
        Xs[lr][kq + 0] = xv.x; Xs[lr][kq + 1] = xv.y;
        Xs[lr][kq + 2] = xv.z; Xs[lr][kq + 3] = xv.w;
        int r = r0 + lr;
        float4 wv = make_float4(0.f, 0.f, 0.f, 0.f);
        if (r < Rt) wv = *(const float4*)(Wt + (size_t)r * ldw + wofs + k0 + kq);
        Ws[lr][kq + 0] = wv.x; Ws[lr][kq + 1] = wv.y;
        Ws[lr][kq + 2] = wv.z; Ws[lr][kq + 3] = wv.w;
        __syncthreads();
#pragma unroll
        for (int k = 0; k < 16; k++) {
            float xr[4], wr[4];
#pragma unroll
            for (int m = 0; m < 4; m++) xr[m] = Xs[ti * 4 + m][k];
#pragma unroll
            for (int n = 0; n < 4; n++) wr[n] = Ws[rj * 4 + n][k];
#pragma unroll
            for (int m = 0; m < 4; m++)
#pragma unroll
                for (int n = 0; n < 4; n++)
                    acc[m][n] = fmaf(xr[m], wr[n], acc[m][n]);
        }
        __syncthreads();
    }
    int rq = r0 + rj * 4;
    if (rq < Rt) {
        float b[4];
#pragma unroll
        for (int n = 0; n < 4; n++) {
            int r = rq + n;
            b[n] = (bias1 ? bias1[r] : 0.f) + (bias2 ? bias2[r] : 0.f);
        }
#pragma unroll
        for (int m = 0; m < 4; m++) {
            int t = t0 + ti * 4 + m;
            float4 o;
            o.x = acc[m][0] + b[0]; o.y = acc[m][1] + b[1];
            o.z = acc[m][2] + b[2]; o.w = acc[m][3] + b[3];
            *(float4*)(out + (size_t)t * ldo + rq) = o;
        }
    }
}

// ---------- init: pack h0 into tagged 64-bit words (tag 0, parity 0) ----------
// wbuf layout per layer: [dir][parity][NPAIRP] u64 ; word = tag | h0<<16 | h1<<32
__global__ void lstm_init3(const float* __restrict__ h0, u64* wbufA, u64* wbufB) {
    int tid = threadIdx.x;
    for (int i = tid; i < 2 * 2 * NPAIRP; i += 256) {
        wbufA[i] = 0xFFFFULL;  // invalid tag
        wbufB[i] = 0xFFFFULL;
    }
    __syncthreads();
    for (int p = tid; p < 2 * NPAIR; p += 256) {
        int d = p / NPAIR, pr = p - d * NPAIR;
        // layer 0
        f16 a0 = (f16)h0[d * H + 2 * pr], b0 = (f16)h0[d * H + 2 * pr + 1];
        wbufA[(size_t)d * 2 * NPAIRP + pr] =
            0ULL | ((u64)f16bits(a0) << 16) | ((u64)f16bits(b0) << 32);
        // layer 1
        f16 a1 = (f16)h0[2 * H + d * H + 2 * pr], b1 = (f16)h0[2 * H + d * H + 2 * pr + 1];
        wbufB[(size_t)d * 2 * NPAIRP + pr] =
            0ULL | ((u64)f16bits(a1) << 16) | ((u64)f16bits(b1) << 32);
    }
}

// ---------- persistent LSTM layer v3: payload-carrying atomics ----------
// grid = 10 blocks (dir = b/5, blk = b%5), 256 threads.
// Block owns h rows [blk*80, +80) (all 4 gates). thread = (jg<16, ksub<16):
// jg owns 5 h-rows, ksub a 26-wide k slice. All cross-block h exchange goes
// through u64 words at the IC via atomic RMWs (exchange to publish,
// fetch_add(0) to read) -- tag==step makes each word self-validating, so no
// fences/flags are needed and per-XCD L2 non-coherence is irrelevant.
__global__ __launch_bounds__(256, 1) void lstm_layer3(
    const float* __restrict__ G,     // [2][T][G4] gate inputs, biases folded
    const float* __restrict__ Whh,   // [2][G4][H]
    const float* __restrict__ c0l,   // [2][H] this layer
    float* __restrict__ xout,        // [T][2H]
    u64* __restrict__ wbuf) {        // [2][2][NPAIRP]
    const int role = blockIdx.x;
    const int dir = role / NBLK_D, blk = role - dir * NBLK_D;
    const int tid = threadIdx.x;
    const int jg = tid >> 4, ksub = tid & 15;
    const int k0 = ksub * 26;
    const int hbase = blk * 80 + jg * 5;
    const float* Wd = Whh + (size_t)dir * G4 * H;
    const float* Gd = G + (size_t)dir * T * G4;
    u64* wd = wbuf + (size_t)dir * 2 * NPAIRP;

    __shared__ f16 hsh[2 * NPAIRP];  // 416 halves (400 live + 16 zero pad)
    __shared__ f16 hpub[80];
    if (tid < 16) hsh[2 * NPAIR + tid] = (f16)0.f;

    // recurrent weights -> registers as half2: 4 gates x 5 rows x 13 pairs
    half2t w[4][5][13];
#pragma unroll
    for (int g = 0; g < 4; ++g)
#pragma unroll
        for (int jj = 0; jj < 5; ++jj) {
            const float* row = Wd + (size_t)(g * H + hbase + jj) * H;
#pragma unroll
            for (int i = 0; i < 13; ++i) {
                int k = k0 + 2 * i;
                float a = (k < H) ? row[k] : 0.f;
                float b = (k + 1 < H) ? row[k + 1] : 0.f;
                half2t hv; hv.x = (_Float16)a; hv.y = (_Float16)b;
                w[g][jj][i] = hv;
            }
        }
    float c[5];
#pragma unroll
    for (int jj = 0; jj < 5; ++jj) c[jj] = c0l[dir * H + hbase + jj];

    float gcur[4][5];
    {
        int tt = dir ? (T - 1) : 0;
        const float* gr = Gd + (size_t)tt * G4;
#pragma unroll
        for (int g = 0; g < 4; ++g)
#pragma unroll
            for (int jj = 0; jj < 5; ++jj) gcur[g][jj] = gr[g * H + hbase + jj];
    }

    const bool fetcher = tid < NPAIR;
    const bool mine = (tid >= blk * 40) && (tid < blk * 40 + 40);

#pragma clang loop unroll(disable)
    for (int s = 0; s < T; ++s) {
        // fetch h_s words (parity s&1, tag s). Own words come via LDS fast-path.
        if (fetcher && (s == 0 || !mine)) {
            u64* src = wd + (size_t)(s & 1) * NPAIRP + tid;
            u64 v = __hip_atomic_fetch_add(src, 0ULL, __ATOMIC_RELAXED,
                                           __HIP_MEMORY_SCOPE_AGENT);
            while ((unsigned)(v & 0xFFFFULL) != (unsigned)s) {
                __builtin_amdgcn_s_sleep(1);
                v = __hip_atomic_fetch_add(src, 0ULL, __ATOMIC_RELAXED,
                                           __HIP_MEMORY_SCOPE_AGENT);
            }
            hsh[2 * tid]     = bits2f16((unsigned short)((v >> 16) & 0xFFFF));
            hsh[2 * tid + 1] = bits2f16((unsigned short)((v >> 32) & 0xFFFF));
        }
        // prefetch next step's G (overlaps the atomic latency)
        float gnext[4][5];
        {
            int sn = (s + 1 < T) ? (s + 1) : s;
            int tt = dir ? (T - 1 - sn) : sn;
            const float* gr = Gd + (size_t)tt * G4;
#pragma unroll
            for (int g = 0; g < 4; ++g)
#pragma unroll
                for (int jj = 0; jj < 5; ++jj) gnext[g][jj] = gr[g * H + hbase + jj];
        }
        __syncthreads();  // (A) all of h_s is in LDS

        half2t h2[13];
        const half2t* hb2 = (const half2t*)hsh;
#pragma unroll
        for (int i = 0; i < 13; ++i) h2[i] = hb2[ksub * 13 + i];

        float sum[4][5];
#pragma unroll
        for (int g = 0; g < 4; ++g)
#pragma unroll
            for (int jj = 0; jj < 5; ++jj) {
                float a = 0.f;
#pragma unroll
                for (int i = 0; i < 13; ++i) a = dot2f(w[g][jj][i], h2[i], a);
                a += __shfl_xor(a, 1);
                a += __shfl_xor(a, 2);
                a += __shfl_xor(a, 4);
                a += __shfl_xor(a, 8);
                sum[g][jj] = a;
            }
        const int tt = dir ? (T - 1 - s) : s;
        if (ksub == 0) {
#pragma unroll
            for (int jj = 0; jj < 5; ++jj) {
                float iv = sum[0][jj] + gcur[0][jj];
                float fv = sum[1][jj] + gcur[1][jj];
                float gv = sum[2][jj] + gcur[2][jj];
                float ov = sum[3][jj] + gcur[3][jj];
                float cn = sigf(fv) * c[jj] + sigf(iv) * tanhf_fast(gv);
                c[jj] = cn;
                float hn = sigf(ov) * tanhf_fast(cn);
                hpub[jg * 5 + jj] = (f16)hn;
                xout[(size_t)tt * (2 * H) + dir * H + hbase + jj] = hn;
            }
        }
        __syncthreads();  // (B) hpub ready; everyone done reading hsh

        if (tid < 40) {
            f16 a = hpub[2 * tid], b = hpub[2 * tid + 1];
            // local fast-path: own slice of h_{s+1} straight into LDS
            hsh[blk * 80 + 2 * tid] = a;
            hsh[blk * 80 + 2 * tid + 1] = b;
            u64 wv = (u64)(unsigned)(s + 1) |
                     ((u64)f16bits(a) << 16) | ((u64)f16bits(b) << 32);
            (void)__hip_atomic_exchange(
                wd + (size_t)((s + 1) & 1) * NPAIRP + blk * 40 + tid, wv,
                __ATOMIC_RELAXED, __HIP_MEMORY_SCOPE_AGENT);
        }
#pragma unroll
        for (int g = 0; g < 4; ++g)
#pragma unroll
            for (int jj = 0; jj < 5; ++jj) gcur[g][jj] = gnext[g][jj];
    }
}

// ---------- fused pairwise scorer ----------
__global__ __launch_bounds__(256) void scores_k(
    const float* __restrict__ pi, const float* __restrict__ pj,
    const float* __restrict__ w2, const float* __restrict__ b2p,
    float* __restrict__ out) {
    __shared__ float Ps[16][401];
    __shared__ float Qs[16][401];
    __shared__ float w2s[400];
    const int tid = threadIdx.x;
    const int i0 = blockIdx.y * 16, j0 = blockIdx.x * 16;
    for (int r = 0; r < 16; r++) {
        for (int k = tid; k < MLP_H; k += 256) {
            Ps[r][k] = pi[(size_t)(i0 + r) * MLP_H + k];
            Qs[r][k] = pj[(size_t)(j0 + r) * MLP_H + k];
        }
    }
    for (int k = tid; k < MLP_H; k += 256) w2s[k] = w2[k];
    __syncthreads();
    const int ti = tid >> 4, tj = tid & 15;
    float acc = 0.f;
#pragma unroll 4
    for (int k = 0; k < MLP_H; k++) {
        float x = Ps[ti][k] + Qs[tj][k];
        acc = fmaf(w2s[k], tanhf_fast(x), acc);
    }
    const int i = i0 + ti, j = j0 + tj;
    out[(size_t)i * T + j] = (i == j) ? 0.f : (acc + b2p[0]);
}

extern "C" void kernel_launch(void* const* d_in, const int* in_sizes, int n_in,
                              void* d_out, int out_size, void* d_ws, size_t ws_size,
                              hipStream_t stream) {
    const int*   words = (const int*)d_in[0];
    const int*   tags  = (const int*)d_in[1];
    const float* wemb  = (const float*)d_in[2];
    const float* temb  = (const float*)d_in[3];
    const float* Wih0  = (const float*)d_in[4];
    const float* Whh0  = (const float*)d_in[5];
    const float* bih0  = (const float*)d_in[6];
    const float* bhh0  = (const float*)d_in[7];
    const float* Wih1  = (const float*)d_in[8];
    const float* Whh1  = (const float*)d_in[9];
    const float* bih1  = (const float*)d_in[10];
    const float* bhh1  = (const float*)d_in[11];
    const float* W1    = (const float*)d_in[12];
    const float* b1    = (const float*)d_in[13];
    const float* W2    = (const float*)d_in[14];
    const float* b2    = (const float*)d_in[15];
    const float* h0    = (const float*)d_in[16];
    const float* c0    = (const float*)d_in[17];
    float* out = (float*)d_out;

    float* W = (float*)d_ws;
    float* x0   = W;                 // 256*400   (dead after layer-0 GEMMs)
    float* x1   = W + 102400;        // 256*800
    float* hvec = W + 307200;        // 256*800
    float* Gb   = W + 512000;        // 2*256*1600 (reused for both layers)
    float* pi   = W + 1331200;       // 256*400
    float* pj   = W + 1433600;       // 256*400
    // word buffers overlap x0's region (x0 is dead before lstm_init3 runs)
    u64* wbufA = (u64*)W;                    // 2*2*208 u64
    u64* wbufB = wbufA + 2 * 2 * NPAIRP;

    // 1. embedding gather
    gather_k<<<T, 128, 0, stream>>>(words, tags, wemb, temb, x0);

    // 2. layer-0 gate inputs
    for (int d = 0; d < 2; d++) {
        gemm_tn<<<dim3(4, 25), 256, 0, stream>>>(
            x0, H, Wih0 + (size_t)d * G4 * H, H, 0,
            bih0 + d * G4, bhh0 + d * G4,
            Gb + (size_t)d * T * G4, G4, G4, H);
    }
    // 3. init packed h0 words (x0 now dead), then LSTM layer 0
    lstm_init3<<<1, 256, 0, stream>>>(h0, wbufA, wbufB);
    lstm_layer3<<<2 * NBLK_D, 256, 0, stream>>>(Gb, Whh0, c0, x1, wbufA);

    // 4. layer-1 gate inputs (K=800)
    for (int d = 0; d < 2; d++) {
        gemm_tn<<<dim3(4, 25), 256, 0, stream>>>(
            x1, 2 * H, Wih1 + (size_t)d * G4 * (2 * H), 2 * H, 0,
            bih1 + d * G4, bhh1 + d * G4,
            Gb + (size_t)d * T * G4, G4, G4, 2 * H);
    }
    // 5. LSTM layer 1
    lstm_layer3<<<2 * NBLK_D, 256, 0, stream>>>(Gb, Whh1, c0 + 2 * H, hvec, wbufB);

    // 6. pi = hvec @ W1a.T + b1 ; pj = hvec @ W1b.T
    gemm_tn<<<dim3(4, 7), 256, 0, stream>>>(
        hvec, 2 * H, W1, G4, 0, b1, nullptr, pi, MLP_H, MLP_H, 2 * H);
    gemm_tn<<<dim3(4, 7), 256, 0, stream>>>(
        hvec, 2 * H, W1, G4, 2 * H, nullptr, nullptr, pj, MLP_H, MLP_H, 2 * H);

    // 7. fused pairwise scores
    scores_k<<<dim3(16, 16), 256, 0, stream>>>(pi, pj, W2, b2, out);
}

// Round 4
// 2958.042 us; speedup vs baseline: 1.0872x; 1.0872x over previous
//
#include <hip/hip_runtime.h>
#include <hip/hip_bf16.h>

#define T 256
#define H 400
#define G4 1600   // 4*H
#define WD 300
#define TD 100
#define MLP_H 400
#define NBLK_D 5        // blocks per direction
#define NPAIR 200       // 400 h values -> 200 packed 64-bit words
#define SLOT_STRIDE 8   // u64s per slot: one slot per 64B cacheline
#define KSL 14          // k elements per ksub lane (32*14 = 448 >= 400)

typedef _Float16 f16;
typedef _Float16 half2t __attribute__((ext_vector_type(2)));
typedef unsigned long long u64;

// ---------- math helpers ----------
__device__ __forceinline__ float fexp(float x) {
    return __builtin_amdgcn_exp2f(x * 1.4426950408889634f);
}
__device__ __forceinline__ float sigf(float x) {
    return __builtin_amdgcn_rcpf(1.0f + fexp(-x));
}
__device__ __forceinline__ float tanhf_fast(float x) {
    return 1.0f - 2.0f * __builtin_amdgcn_rcpf(1.0f + fexp(2.0f * x));
}
__device__ __forceinline__ unsigned short f16bits(f16 x) {
    union { f16 h; unsigned short u; } v; v.h = x; return v.u;
}
__device__ __forceinline__ f16 bits2f16(unsigned short u) {
    union { f16 h; unsigned short u; } v; v.u = u; return v.h;
}

#if __has_builtin(__builtin_amdgcn_fdot2)
__device__ __forceinline__ float dot2f(half2t a, half2t b, float c) {
    return __builtin_amdgcn_fdot2(a, b, c, false);
}
#else
__device__ __forceinline__ float dot2f(half2t a, half2t b, float c) {
    return fmaf((float)a.y, (float)b.y, fmaf((float)a.x, (float)b.x, c));
}
#endif

// ---------- embedding gather ----------
__global__ void gather_k(const int* __restrict__ words, const int* __restrict__ tags,
                         const float* __restrict__ wemb, const float* __restrict__ temb,
                         float* __restrict__ x0) {
    int t = blockIdx.x;
    int w = words[t], g = tags[t];
    for (int c = threadIdx.x; c < H; c += 128) {
        float v = (c < WD) ? wemb[w * WD + c] : temb[g * TD + (c - WD)];
        x0[t * H + c] = v;
    }
}

// ---------- generic GEMM: out[t][r] = sum_k X[t*ldx+k]*W[r*ldw+wofs+k] + bias1[r]+bias2[r]
__global__ __launch_bounds__(256) void gemm_tn(
    const float* __restrict__ X, int ldx,
    const float* __restrict__ Wt, int ldw, int wofs,
    const float* __restrict__ bias1, const float* __restrict__ bias2,
    float* __restrict__ out, int ldo, int Rt, int K) {
    __shared__ float Xs[64][17];
    __shared__ float Ws[64][17];
    const int tid = threadIdx.x;
    const int t0 = blockIdx.x * 64, r0 = blockIdx.y * 64;
    const int lr = tid >> 2, kq = (tid & 3) * 4;
    const int ti = tid >> 4, rj = tid & 15;
    float acc[4][4] = {};
    for (int k0 = 0; k0 < K; k0 += 16) {
        float4 xv = *(const float4*)(X + (size_t)(t0 + lr) * ldx + k0 + kq);
        Xs[lr][kq + 0] = xv.x; Xs[lr][kq + 1] = xv.y;
        Xs[lr][kq + 2] = xv.z; Xs[lr][kq + 3] = xv.w;
        int r = r0 + lr;
        float4 wv = make_float4(0.f, 0.f, 0.f, 0.f);
        if (r < Rt) wv = *(const float4*)(Wt + (size_t)r * ldw + wofs + k0 + kq);
        Ws[lr][kq + 0] = wv.x; Ws[lr][kq + 1] = wv.y;
        Ws[lr][kq + 2] = wv.z; Ws[lr][kq + 3] = wv.w;
        __syncthreads();
#pragma unroll
        for (int k = 0; k < 16; k++) {
            float xr[4], wr[4];
#pragma unroll
            for (int m = 0; m < 4; m++) xr[m] = Xs[ti * 4 + m][k];
#pragma unroll
            for (int n = 0; n < 4; n++) wr[n] = Ws[rj * 4 + n][k];
#pragma unroll
            for (int m = 0; m < 4; m++)
#pragma unroll
                for (int n = 0; n < 4; n++)
                    acc[m][n] = fmaf(xr[m], wr[n], acc[m][n]);
        }
        __syncthreads();
    }
    int rq = r0 + rj * 4;
    if (rq < Rt) {
        float b[4];
#pragma unroll
        for (int n = 0; n < 4; n++) {
            int r = rq + n;
            b[n] = (bias1 ? bias1[r] : 0.f) + (bias2 ? bias2[r] : 0.f);
        }
#pragma unroll
        for (int m = 0; m < 4; m++) {
            int t = t0 + ti * 4 + m;
            float4 o;
            o.x = acc[m][0] + b[0]; o.y = acc[m][1] + b[1];
            o.z = acc[m][2] + b[2]; o.w = acc[m][3] + b[3];
            *(float4*)(out + (size_t)t * ldo + rq) = o;
        }
    }
}

// ---------- init: tagged slots, one per cacheline ----------
// slot layout per layer: [dir][parity][NPAIR] u64 at stride SLOT_STRIDE
__global__ void lstm_init4(const float* __restrict__ h0, u64* sA, u64* sB) {
    int tid = threadIdx.x;
    const int TOT = 2 * 2 * NPAIR * SLOT_STRIDE;
    for (int i = tid; i < TOT; i += 256) { sA[i] = 0xFFFFULL; sB[i] = 0xFFFFULL; }
    __syncthreads();
    for (int p = tid; p < 2 * NPAIR; p += 256) {
        int d = p / NPAIR, pr = p - d * NPAIR;
        size_t off = (size_t)((d * 2 + 0) * NPAIR + pr) * SLOT_STRIDE;
        f16 a0 = (f16)h0[d * H + 2 * pr], b0 = (f16)h0[d * H + 2 * pr + 1];
        sA[off] = 0ULL | ((u64)f16bits(a0) << 16) | ((u64)f16bits(b0) << 32);
        f16 a1 = (f16)h0[2 * H + d * H + 2 * pr], b1 = (f16)h0[2 * H + d * H + 2 * pr + 1];
        sB[off] = 0ULL | ((u64)f16bits(a1) << 16) | ((u64)f16bits(b1) << 32);
    }
}

// ---------- persistent LSTM layer v4 ----------
// grid = 10 blocks (dir = b/5, blk = b%5), 512 threads.
// Block owns h rows [blk*80,+80). jg = tid>>5 owns 5 rows (all 4 gates);
// ksub = tid&31 owns k slice [ksub*14, +14). Waves 0-3 poll foreign h words
// (one lane per word, one word per cacheline -> no same-line serialization);
// waves 4-7 stage next step's G into LDS. Publish via payload-carrying
// atomic_exchange (tag = step), fetch via fetch_add(0): RMWs execute at the
// coherence point, so per-XCD L2 non-coherence is irrelevant; no fences.
__global__ __launch_bounds__(512, 2) void lstm_layer4(
    const float* __restrict__ G,     // [2][T][G4] gate inputs, biases folded
    const float* __restrict__ Whh,   // [2][G4][H]
    const float* __restrict__ c0l,   // [2][H] this layer
    float* __restrict__ xout,        // [T][2H]
    u64* __restrict__ slots) {       // [2][2][NPAIR] stride SLOT_STRIDE
    const int role = blockIdx.x;
    const int dir = role / NBLK_D, blk = role - dir * NBLK_D;
    const int tid = threadIdx.x;
    const int jg = tid >> 5, ksub = tid & 31;
    const int k0 = ksub * KSL;
    const int hbase = blk * 80 + jg * 5;
    const float* Wd = Whh + (size_t)dir * G4 * H;
    const float* Gd = G + (size_t)dir * T * G4;

    __shared__ f16 hsh[32 * KSL];     // 448 halves: h_s (400 live + 48 zero pad)
    __shared__ f16 hpub[80];
    __shared__ float gsh[2][320];     // staged G, double-buffered: [par][g*80+r]

    // recurrent weights -> registers: 4 gates x 5 rows x 7 half2 (k slice)
    half2t w[4][5][7];
#pragma unroll
    for (int g = 0; g < 4; ++g)
#pragma unroll
        for (int jj = 0; jj < 5; ++jj) {
            const float* row = Wd + (size_t)(g * H + hbase + jj) * H;
#pragma unroll
            for (int i = 0; i < 7; ++i) {
                int k = k0 + 2 * i;
                float a = (k < H) ? row[k] : 0.f;
                float b = (k + 1 < H) ? row[k + 1] : 0.f;
                half2t hv; hv.x = (_Float16)a; hv.y = (_Float16)b;
                w[g][jj][i] = hv;
            }
        }
    float c[5];
#pragma unroll
    for (int jj = 0; jj < 5; ++jj) c[jj] = c0l[dir * H + hbase + jj];

    // pre-stage G(0); zero hsh pad
    if (tid >= 256) {
        int tt0 = dir ? (T - 1) : 0;
        for (int i = tid - 256; i < 320; i += 256) {
            int g = i / 80, r = i - g * 80;
            gsh[0][i] = Gd[(size_t)tt0 * G4 + g * H + blk * 80 + r];
        }
    }
    if (tid < 48) hsh[2 * NPAIR + tid] = (f16)0.f;
    __syncthreads();

#pragma clang loop unroll(disable)
    for (int s = 0; s < T; ++s) {
        // waves 0-3: fetch h_s words (parity s&1, tag s); own words via LDS fast-path
        if (tid < NPAIR) {
            bool own = (tid >= blk * 40) && (tid < blk * 40 + 40);
            if (s == 0 || !own) {
                u64* src = slots + (size_t)((dir * 2 + (s & 1)) * NPAIR + tid) * SLOT_STRIDE;
                u64 v = __hip_atomic_fetch_add(src, 0ULL, __ATOMIC_RELAXED,
                                               __HIP_MEMORY_SCOPE_AGENT);
                while ((unsigned)(v & 0xFFFFULL) != (unsigned)s) {
                    __builtin_amdgcn_s_sleep(1);
                    v = __hip_atomic_fetch_add(src, 0ULL, __ATOMIC_RELAXED,
                                               __HIP_MEMORY_SCOPE_AGENT);
                }
                hsh[2 * tid]     = bits2f16((unsigned short)((v >> 16) & 0xFFFF));
                hsh[2 * tid + 1] = bits2f16((unsigned short)((v >> 32) & 0xFFFF));
            }
        } else if (tid >= 256) {
            // waves 4-7: stage G(s+1) into the other parity half
            int sn = (s + 1 < T) ? (s + 1) : s;
            int tt = dir ? (T - 1 - sn) : sn;
            for (int i = tid - 256; i < 320; i += 256) {
                int g = i / 80, r = i - g * 80;
                gsh[(s + 1) & 1][i] = Gd[(size_t)tt * G4 + g * H + blk * 80 + r];
            }
        }
        __syncthreads();  // (A) h_s complete in LDS; G(s) staged since last step

        half2t h2[7];
        const half2t* hb2 = (const half2t*)hsh;
#pragma unroll
        for (int i = 0; i < 7; ++i) h2[i] = hb2[ksub * 7 + i];

        float sum[4][5];
#pragma unroll
        for (int g = 0; g < 4; ++g)
#pragma unroll
            for (int jj = 0; jj < 5; ++jj) {
                float a = 0.f;
#pragma unroll
                for (int i = 0; i < 7; ++i) a = dot2f(w[g][jj][i], h2[i], a);
                a += __shfl_xor(a, 1);
                a += __shfl_xor(a, 2);
                a += __shfl_xor(a, 4);
                a += __shfl_xor(a, 8);
                a += __shfl_xor(a, 16);
                sum[g][jj] = a;
            }
        const int tt = dir ? (T - 1 - s) : s;
        if (ksub == 0) {
            const float* gc = gsh[s & 1];
#pragma unroll
            for (int jj = 0; jj < 5; ++jj) {
                int r = jg * 5 + jj;
                float iv = sum[0][jj] + gc[0 * 80 + r];
                float fv = sum[1][jj] + gc[1 * 80 + r];
                float gv = sum[2][jj] + gc[2 * 80 + r];
                float ov = sum[3][jj] + gc[3 * 80 + r];
                float cn = sigf(fv) * c[jj] + sigf(iv) * tanhf_fast(gv);
                c[jj] = cn;
                float hn = sigf(ov) * tanhf_fast(cn);
                hpub[r] = (f16)hn;
                xout[(size_t)tt * (2 * H) + dir * H + hbase + jj] = hn;
            }
        }
        __syncthreads();  // (B) hpub ready; all done reading hsh

        if (tid < 40) {
            f16 a = hpub[2 * tid], b = hpub[2 * tid + 1];
            hsh[blk * 80 + 2 * tid] = a;       // own slice of h_{s+1}, LDS fast-path
            hsh[blk * 80 + 2 * tid + 1] = b;
            u64 wv = (u64)(unsigned)(s + 1) |
                     ((u64)f16bits(a) << 16) | ((u64)f16bits(b) << 32);
            (void)__hip_atomic_exchange(
                slots + (size_t)((dir * 2 + ((s + 1) & 1)) * NPAIR + blk * 40 + tid) * SLOT_STRIDE,
                wv, __ATOMIC_RELAXED, __HIP_MEMORY_SCOPE_AGENT);
        }
    }
}

// ---------- fused pairwise scorer ----------
__global__ __launch_bounds__(256) void scores_k(
    const float* __restrict__ pi, const float* __restrict__ pj,
    const float* __restrict__ w2, const float* __restrict__ b2p,
    float* __restrict__ out) {
    __shared__ float Ps[16][401];
    __shared__ float Qs[16][401];
    __shared__ float w2s[400];
    const int tid = threadIdx.x;
    const int i0 = blockIdx.y * 16, j0 = blockIdx.x * 16;
    for (int r = 0; r < 16; r++) {
        for (int k = tid; k < MLP_H; k += 256) {
            Ps[r][k] = pi[(size_t)(i0 + r) * MLP_H + k];
            Qs[r][k] = pj[(size_t)(j0 + r) * MLP_H + k];
        }
    }
    for (int k = tid; k < MLP_H; k += 256) w2s[k] = w2[k];
    __syncthreads();
    const int ti = tid >> 4, tj = tid & 15;
    float acc = 0.f;
#pragma unroll 4
    for (int k = 0; k < MLP_H; k++) {
        float x = Ps[ti][k] + Qs[tj][k];
        acc = fmaf(w2s[k], tanhf_fast(x), acc);
    }
    const int i = i0 + ti, j = j0 + tj;
    out[(size_t)i * T + j] = (i == j) ? 0.f : (acc + b2p[0]);
}

extern "C" void kernel_launch(void* const* d_in, const int* in_sizes, int n_in,
                              void* d_out, int out_size, void* d_ws, size_t ws_size,
                              hipStream_t stream) {
    const int*   words = (const int*)d_in[0];
    const int*   tags  = (const int*)d_in[1];
    const float* wemb  = (const float*)d_in[2];
    const float* temb  = (const float*)d_in[3];
    const float* Wih0  = (const float*)d_in[4];
    const float* Whh0  = (const float*)d_in[5];
    const float* bih0  = (const float*)d_in[6];
    const float* bhh0  = (const float*)d_in[7];
    const float* Wih1  = (const float*)d_in[8];
    const float* Whh1  = (const float*)d_in[9];
    const float* bih1  = (const float*)d_in[10];
    const float* bhh1  = (const float*)d_in[11];
    const float* W1    = (const float*)d_in[12];
    const float* b1    = (const float*)d_in[13];
    const float* W2    = (const float*)d_in[14];
    const float* b2    = (const float*)d_in[15];
    const float* h0    = (const float*)d_in[16];
    const float* c0    = (const float*)d_in[17];
    float* out = (float*)d_out;

    float* W = (float*)d_ws;
    float* x0   = W;                 // 256*400 (dead after layer-0 GEMMs)
    float* x1   = W + 102400;        // 256*800
    float* hvec = W + 307200;        // 256*800
    float* Gb   = W + 512000;        // 2*256*1600 (reused for both layers)
    float* pi   = W + 1331200;       // 256*400
    float* pj   = W + 1433600;       // 256*400
    // slot arrays overlap x0's region (x0 dead before lstm_init4 runs)
    u64* slotsA = (u64*)W;                               // 6400 u64 = 12800 floats
    u64* slotsB = (u64*)(W + 12800);                     // 6400 u64

    // 1. embedding gather
    gather_k<<<T, 128, 0, stream>>>(words, tags, wemb, temb, x0);

    // 2. layer-0 gate inputs
    for (int d = 0; d < 2; d++) {
        gemm_tn<<<dim3(4, 25), 256, 0, stream>>>(
            x0, H, Wih0 + (size_t)d * G4 * H, H, 0,
            bih0 + d * G4, bhh0 + d * G4,
            Gb + (size_t)d * T * G4, G4, G4, H);
    }
    // 3. init slots (x0 now dead), then LSTM layer 0
    lstm_init4<<<1, 256, 0, stream>>>(h0, slotsA, slotsB);
    lstm_layer4<<<2 * NBLK_D, 512, 0, stream>>>(Gb, Whh0, c0, x1, slotsA);

    // 4. layer-1 gate inputs (K=800)
    for (int d = 0; d < 2; d++) {
        gemm_tn<<<dim3(4, 25), 256, 0, stream>>>(
            x1, 2 * H, Wih1 + (size_t)d * G4 * (2 * H), 2 * H, 0,
            bih1 + d * G4, bhh1 + d * G4,
            Gb + (size_t)d * T * G4, G4, G4, 2 * H);
    }
    // 5. LSTM layer 1
    lstm_layer4<<<2 * NBLK_D, 512, 0, stream>>>(Gb, Whh1, c0 + 2 * H, hvec, slotsB);

    // 6. pi = hvec @ W1a.T + b1 ; pj = hvec @ W1b.T
    gemm_tn<<<dim3(4, 7), 256, 0, stream>>>(
        hvec, 2 * H, W1, G4, 0, b1, nullptr, pi, MLP_H, MLP_H, 2 * H);
    gemm_tn<<<dim3(4, 7), 256, 0, stream>>>(
        hvec, 2 * H, W1, G4, 2 * H, nullptr, nullptr, pj, MLP_H, MLP_H, 2 * H);

    // 7. fused pairwise scores
    scores_k<<<dim3(16, 16), 256, 0, stream>>>(pi, pj, W2, b2, out);
}

// Round 5
// 2640.238 us; speedup vs baseline: 1.2181x; 1.1204x over previous
//
#include <hip/hip_runtime.h>
#include <hip/hip_bf16.h>

#define T 256
#define H 400
#define G4 1600   // 4*H
#define WD 300
#define TD 100
#define MLP_H 400
#define NBLK_D 5        // blocks per direction
#define NPAIR 200       // 400 h values -> 200 tagged 64-bit words
#define KSL 14          // k elements per ksub lane (32*14 = 448 >= 400)

typedef _Float16 f16;
typedef _Float16 half2t __attribute__((ext_vector_type(2)));
typedef unsigned long long u64;
typedef unsigned int u32;

// ---------- math helpers ----------
__device__ __forceinline__ float fexp(float x) {
    return __builtin_amdgcn_exp2f(x * 1.4426950408889634f);
}
__device__ __forceinline__ float sigf(float x) {
    return __builtin_amdgcn_rcpf(1.0f + fexp(-x));
}
__device__ __forceinline__ float tanhf_fast(float x) {
    return 1.0f - 2.0f * __builtin_amdgcn_rcpf(1.0f + fexp(2.0f * x));
}
__device__ __forceinline__ unsigned short f16bits(f16 x) {
    union { f16 h; unsigned short u; } v; v.h = x; return v.u;
}

#if __has_builtin(__builtin_amdgcn_fdot2)
__device__ __forceinline__ float dot2f(half2t a, half2t b, float c) {
    return __builtin_amdgcn_fdot2(a, b, c, false);
}
#else
__device__ __forceinline__ float dot2f(half2t a, half2t b, float c) {
    return fmaf((float)a.y, (float)b.y, fmaf((float)a.x, (float)b.x, c));
}
#endif

// system-scope (sc0 sc1) plain ops: bypass L1/L2, serviced at the IC --
// coherent across XCDs without RMWs or fences.
__device__ __forceinline__ u64 sysload(const u64* p) {
    return __hip_atomic_load(p, __ATOMIC_RELAXED, __HIP_MEMORY_SCOPE_SYSTEM);
}
__device__ __forceinline__ void sysstore(u64* p, u64 v) {
    __hip_atomic_store(p, v, __ATOMIC_RELAXED, __HIP_MEMORY_SCOPE_SYSTEM);
}

// ---------- embedding gather ----------
__global__ void gather_k(const int* __restrict__ words, const int* __restrict__ tags,
                         const float* __restrict__ wemb, const float* __restrict__ temb,
                         float* __restrict__ x0) {
    int t = blockIdx.x;
    int w = words[t], g = tags[t];
    for (int c = threadIdx.x; c < H; c += 128) {
        float v = (c < WD) ? wemb[w * WD + c] : temb[g * TD + (c - WD)];
        x0[t * H + c] = v;
    }
}

// ---------- generic GEMM: out[t][r] = sum_k X[t*ldx+k]*W[r*ldw+wofs+k] + bias1[r]+bias2[r]
__global__ __launch_bounds__(256) void gemm_tn(
    const float* __restrict__ X, int ldx,
    const float* __restrict__ Wt, int ldw, int wofs,
    const float* __restrict__ bias1, const float* __restrict__ bias2,
    float* __restrict__ out, int ldo, int Rt, int K) {
    __shared__ float Xs[64][17];
    __shared__ float Ws[64][17];
    const int tid = threadIdx.x;
    const int t0 = blockIdx.x * 64, r0 = blockIdx.y * 64;
    const int lr = tid >> 2, kq = (tid & 3) * 4;
    const int ti = tid >> 4, rj = tid & 15;
    float acc[4][4] = {};
    for (int k0 = 0; k0 < K; k0 += 16) {
        float4 xv = *(const float4*)(X + (size_t)(t0 + lr) * ldx + k0 + kq);
        Xs[lr][kq + 0] = xv.x; Xs[lr][kq + 1] = xv.y;
        Xs[lr][kq + 2] = xv.z; Xs[lr][kq + 3] = xv.w;
        int r = r0 + lr;
        float4 wv = make_float4(0.f, 0.f, 0.f, 0.f);
        if (r < Rt) wv = *(const float4*)(Wt + (size_t)r * ldw + wofs + k0 + kq);
        Ws[lr][kq + 0] = wv.x; Ws[lr][kq + 1] = wv.y;
        Ws[lr][kq + 2] = wv.z; Ws[lr][kq + 3] = wv.w;
        __syncthreads();
#pragma unroll
        for (int k = 0; k < 16; k++) {
            float xr[4], wr[4];
#pragma unroll
            for (int m = 0; m < 4; m++) xr[m] = Xs[ti * 4 + m][k];
#pragma unroll
            for (int n = 0; n < 4; n++) wr[n] = Ws[rj * 4 + n][k];
#pragma unroll
            for (int m = 0; m < 4; m++)
#pragma unroll
                for (int n = 0; n < 4; n++)
                    acc[m][n] = fmaf(xr[m], wr[n], acc[m][n]);
        }
        __syncthreads();
    }
    int rq = r0 + rj * 4;
    if (rq < Rt) {
        float b[4];
#pragma unroll
        for (int n = 0; n < 4; n++) {
            int r = rq + n;
            b[n] = (bias1 ? bias1[r] : 0.f) + (bias2 ? bias2[r] : 0.f);
        }
#pragma unroll
        for (int m = 0; m < 4; m++) {
            int t = t0 + ti * 4 + m;
            float4 o;
            o.x = acc[m][0] + b[0]; o.y = acc[m][1] + b[1];
            o.z = acc[m][2] + b[2]; o.w = acc[m][3] + b[3];
            *(float4*)(out + (size_t)t * ldo + rq) = o;
        }
    }
}

// ---------- init: tagged words, contiguous [dir][parity][NPAIR] ----------
__global__ void lstm_init5(const float* __restrict__ h0, u64* sA, u64* sB) {
    int tid = threadIdx.x;
    const int TOT = 2 * 2 * NPAIR;
    for (int i = tid; i < TOT; i += 256) { sA[i] = 0xFFFFULL; sB[i] = 0xFFFFULL; }
    __syncthreads();
    for (int p = tid; p < 2 * NPAIR; p += 256) {
        int d = p / NPAIR, pr = p - d * NPAIR;
        size_t off = (size_t)(d * 2 + 0) * NPAIR + pr;   // parity 0, tag 0
        f16 a0 = (f16)h0[d * H + 2 * pr], b0 = (f16)h0[d * H + 2 * pr + 1];
        sA[off] = 0ULL | ((u64)f16bits(a0) << 16) | ((u64)f16bits(b0) << 32);
        f16 a1 = (f16)h0[2 * H + d * H + 2 * pr], b1 = (f16)h0[2 * H + d * H + 2 * pr + 1];
        sB[off] = 0ULL | ((u64)f16bits(a1) << 16) | ((u64)f16bits(b1) << 32);
    }
}

// ---------- persistent LSTM layer v5: system-scope tagged words ----------
// grid = 10 blocks (dir = b/5, blk = b%5), 512 threads.
// Block owns h rows [blk*80,+80). jg = tid>>5 owns 5 rows (all 4 gates);
// ksub = tid&31 owns k slice [ksub*14,+14). Cross-block h exchange:
// producer system-stores tagged u64 words (tag = step, payload = 2 fp16);
// consumers system-load-poll (sc0 sc1 -> IC-direct, parallel, no RMW).
// Tag self-validation makes ordering/fences unnecessary. RMW fallback after
// 16k spins guarantees progress under any cache-semantics surprise.
__global__ __launch_bounds__(512, 2) void lstm_layer5(
    const float* __restrict__ G,     // [2][T][G4] gate inputs, biases folded
    const float* __restrict__ Whh,   // [2][G4][H]
    const float* __restrict__ c0l,   // [2][H] this layer
    float* __restrict__ xout,        // [T][2H]
    u64* __restrict__ slots) {       // [2][2][NPAIR]
    const int role = blockIdx.x;
    const int dir = role / NBLK_D, blk = role - dir * NBLK_D;
    const int tid = threadIdx.x;
    const int jg = tid >> 5, ksub = tid & 31;
    const int k0 = ksub * KSL;
    const int hbase = blk * 80 + jg * 5;
    const float* Wd = Whh + (size_t)dir * G4 * H;
    const float* Gd = G + (size_t)dir * T * G4;
    u64* sd = slots + (size_t)dir * 2 * NPAIR;

    __shared__ u32 hsh32[32 * KSL / 2];   // 224 u32 = 448 halves (400 live + pad)
    __shared__ f16 hpub[80];
    __shared__ float gsh[2][320];         // staged G, double-buffered: [par][g*80+r]

    // recurrent weights -> registers: 4 gates x 5 rows x 7 half2 (k slice)
    half2t w[4][5][7];
#pragma unroll
    for (int g = 0; g < 4; ++g)
#pragma unroll
        for (int jj = 0; jj < 5; ++jj) {
            const float* row = Wd + (size_t)(g * H + hbase + jj) * H;
#pragma unroll
            for (int i = 0; i < 7; ++i) {
                int k = k0 + 2 * i;
                float a = (k < H) ? row[k] : 0.f;
                float b = (k + 1 < H) ? row[k + 1] : 0.f;
                half2t hv; hv.x = (_Float16)a; hv.y = (_Float16)b;
                w[g][jj][i] = hv;
            }
        }
    float c[5];
#pragma unroll
    for (int jj = 0; jj < 5; ++jj) c[jj] = c0l[dir * H + hbase + jj];

    // pre-stage G(0); own h0 words; zero hsh pad
    if (tid >= 256) {
        int tt0 = dir ? (T - 1) : 0;
        for (int i = tid - 256; i < 320; i += 256) {
            int g = i / 80, r = i - g * 80;
            gsh[0][i] = Gd[(size_t)tt0 * G4 + g * H + blk * 80 + r];
        }
    } else if (tid >= 200 && tid < 224) {
        hsh32[tid] = 0u;                  // pad words 200..223
    } else if (tid < 40) {
        u64 v = sysload(sd + 0 * NPAIR + blk * 40 + tid);   // own h0 (tag 0)
        hsh32[blk * 40 + tid] = (u32)(v >> 16);
    }
    __syncthreads();

#pragma clang loop unroll(disable)
    for (int s = 0; s < T; ++s) {
        // 160 poller lanes fetch the 160 foreign words (parity s&1, tag s)
        if (tid < 160) {
            int widx = tid + (tid >= blk * 40 ? 40 : 0);
            u64* src = sd + (size_t)(s & 1) * NPAIR + widx;
            u64 v = sysload(src);
            int spins = 0;
            while ((unsigned)(v & 0xFFFFULL) != (unsigned)s) {
                if (++spins > 16384) {
                    v = __hip_atomic_fetch_add(src, 0ULL, __ATOMIC_RELAXED,
                                               __HIP_MEMORY_SCOPE_AGENT);
                } else {
                    v = sysload(src);
                }
            }
            hsh32[widx] = (u32)(v >> 16);
        } else if (tid >= 256) {
            // waves 4-7: stage G(s+1) into the other parity half
            int sn = (s + 1 < T) ? (s + 1) : s;
            int tt = dir ? (T - 1 - sn) : sn;
            for (int i = tid - 256; i < 320; i += 256) {
                int g = i / 80, r = i - g * 80;
                gsh[(s + 1) & 1][i] = Gd[(size_t)tt * G4 + g * H + blk * 80 + r];
            }
        }
        __syncthreads();  // (A) h_s complete in LDS; G(s) staged since last step

        half2t h2[7];
        const half2t* hb2 = (const half2t*)hsh32;
#pragma unroll
        for (int i = 0; i < 7; ++i) h2[i] = hb2[ksub * 7 + i];

        float sum[4][5];
#pragma unroll
        for (int g = 0; g < 4; ++g)
#pragma unroll
            for (int jj = 0; jj < 5; ++jj) {
                float a = 0.f;
#pragma unroll
                for (int i = 0; i < 7; ++i) a = dot2f(w[g][jj][i], h2[i], a);
                a += __shfl_xor(a, 1);
                a += __shfl_xor(a, 2);
                a += __shfl_xor(a, 4);
                a += __shfl_xor(a, 8);
                a += __shfl_xor(a, 16);
                sum[g][jj] = a;
            }
        // gate math on ALL lanes (identical inputs -> no divergent serial tail)
        const float* gc = gsh[s & 1];
        float hnew[5];
#pragma unroll
        for (int jj = 0; jj < 5; ++jj) {
            int r = jg * 5 + jj;
            float iv = sum[0][jj] + gc[0 * 80 + r];
            float fv = sum[1][jj] + gc[1 * 80 + r];
            float gv = sum[2][jj] + gc[2 * 80 + r];
            float ov = sum[3][jj] + gc[3 * 80 + r];
            float cn = sigf(fv) * c[jj] + sigf(iv) * tanhf_fast(gv);
            c[jj] = cn;
            hnew[jj] = sigf(ov) * tanhf_fast(cn);
        }
        const int tt = dir ? (T - 1 - s) : s;
        if (ksub == 0) {
#pragma unroll
            for (int jj = 0; jj < 5; ++jj) {
                hpub[jg * 5 + jj] = (f16)hnew[jj];
                xout[(size_t)tt * (2 * H) + dir * H + hbase + jj] = hnew[jj];
            }
        }
        __syncthreads();  // (B) hpub ready; all done reading hsh

        if (tid < 40) {
            f16 a = hpub[2 * tid], b = hpub[2 * tid + 1];
            u32 pk = (u32)f16bits(a) | ((u32)f16bits(b) << 16);
            hsh32[blk * 40 + tid] = pk;       // own slice of h_{s+1}, LDS fast-path
            sysstore(sd + (size_t)((s + 1) & 1) * NPAIR + blk * 40 + tid,
                     (u64)(unsigned)(s + 1) | ((u64)pk << 16));
        }
    }
}

// ---------- fused pairwise scorer ----------
__global__ __launch_bounds__(256) void scores_k(
    const float* __restrict__ pi, const float* __restrict__ pj,
    const float* __restrict__ w2, const float* __restrict__ b2p,
    float* __restrict__ out) {
    __shared__ float Ps[16][401];
    __shared__ float Qs[16][401];
    __shared__ float w2s[400];
    const int tid = threadIdx.x;
    const int i0 = blockIdx.y * 16, j0 = blockIdx.x * 16;
    for (int r = 0; r < 16; r++) {
        for (int k = tid; k < MLP_H; k += 256) {
            Ps[r][k] = pi[(size_t)(i0 + r) * MLP_H + k];
            Qs[r][k] = pj[(size_t)(j0 + r) * MLP_H + k];
        }
    }
    for (int k = tid; k < MLP_H; k += 256) w2s[k] = w2[k];
    __syncthreads();
    const int ti = tid >> 4, tj = tid & 15;
    float acc = 0.f;
#pragma unroll 4
    for (int k = 0; k < MLP_H; k++) {
        float x = Ps[ti][k] + Qs[tj][k];
        acc = fmaf(w2s[k], tanhf_fast(x), acc);
    }
    const int i = i0 + ti, j = j0 + tj;
    out[(size_t)i * T + j] = (i == j) ? 0.f : (acc + b2p[0]);
}

extern "C" void kernel_launch(void* const* d_in, const int* in_sizes, int n_in,
                              void* d_out, int out_size, void* d_ws, size_t ws_size,
                              hipStream_t stream) {
    const int*   words = (const int*)d_in[0];
    const int*   tags  = (const int*)d_in[1];
    const float* wemb  = (const float*)d_in[2];
    const float* temb  = (const float*)d_in[3];
    const float* Wih0  = (const float*)d_in[4];
    const float* Whh0  = (const float*)d_in[5];
    const float* bih0  = (const float*)d_in[6];
    const float* bhh0  = (const float*)d_in[7];
    const float* Wih1  = (const float*)d_in[8];
    const float* Whh1  = (const float*)d_in[9];
    const float* bih1  = (const float*)d_in[10];
    const float* bhh1  = (const float*)d_in[11];
    const float* W1    = (const float*)d_in[12];
    const float* b1    = (const float*)d_in[13];
    const float* W2    = (const float*)d_in[14];
    const float* b2    = (const float*)d_in[15];
    const float* h0    = (const float*)d_in[16];
    const float* c0    = (const float*)d_in[17];
    float* out = (float*)d_out;

    float* W = (float*)d_ws;
    float* x0   = W;                 // 256*400 (dead after layer-0 GEMMs)
    float* x1   = W + 102400;        // 256*800
    float* hvec = W + 307200;        // 256*800
    float* Gb   = W + 512000;        // 2*256*1600 (reused for both layers)
    float* pi   = W + 1331200;       // 256*400
    float* pj   = W + 1433600;       // 256*400
    // word arrays overlap x0's region (x0 dead before lstm_init5 runs)
    u64* slotsA = (u64*)W;                               // 800 u64
    u64* slotsB = (u64*)(W + 2048);                      // 800 u64

    // 1. embedding gather
    gather_k<<<T, 128, 0, stream>>>(words, tags, wemb, temb, x0);

    // 2. layer-0 gate inputs
    for (int d = 0; d < 2; d++) {
        gemm_tn<<<dim3(4, 25), 256, 0, stream>>>(
            x0, H, Wih0 + (size_t)d * G4 * H, H, 0,
            bih0 + d * G4, bhh0 + d * G4,
            Gb + (size_t)d * T * G4, G4, G4, H);
    }
    // 3. init tagged words (x0 now dead), then LSTM layer 0
    lstm_init5<<<1, 256, 0, stream>>>(h0, slotsA, slotsB);
    lstm_layer5<<<2 * NBLK_D, 512, 0, stream>>>(Gb, Whh0, c0, x1, slotsA);

    // 4. layer-1 gate inputs (K=800)
    for (int d = 0; d < 2; d++) {
        gemm_tn<<<dim3(4, 25), 256, 0, stream>>>(
            x1, 2 * H, Wih1 + (size_t)d * G4 * (2 * H), 2 * H, 0,
            bih1 + d * G4, bhh1 + d * G4,
            Gb + (size_t)d * T * G4, G4, G4, 2 * H);
    }
    // 5. LSTM layer 1
    lstm_layer5<<<2 * NBLK_D, 512, 0, stream>>>(Gb, Whh1, c0 + 2 * H, hvec, slotsB);

    // 6. pi = hvec @ W1a.T + b1 ; pj = hvec @ W1b.T
    gemm_tn<<<dim3(4, 7), 256, 0, stream>>>(
        hvec, 2 * H, W1, G4, 0, b1, nullptr, pi, MLP_H, MLP_H, 2 * H);
    gemm_tn<<<dim3(4, 7), 256, 0, stream>>>(
        hvec, 2 * H, W1, G4, 2 * H, nullptr, nullptr, pj, MLP_H, MLP_H, 2 * H);

    // 7. fused pairwise scores
    scores_k<<<dim3(16, 16), 256, 0, stream>>>(pi, pj, W2, b2, out);
}

// Round 6
// 1799.193 us; speedup vs baseline: 1.7875x; 1.4675x over previous
//
#include <hip/hip_runtime.h>
#include <hip/hip_bf16.h>

#define T 256
#define H 400
#define G4 1600   // 4*H
#define WD 300
#define TD 100
#define MLP_H 400
#define NBLK_D 5        // blocks per direction
#define NPAIR 200       // 400 h values -> 200 tagged 64-bit words

typedef _Float16 f16;
typedef _Float16 half2t __attribute__((ext_vector_type(2)));
typedef unsigned long long u64;
typedef unsigned int u32;

// ---------- math helpers ----------
__device__ __forceinline__ float fexp(float x) {
    return __builtin_amdgcn_exp2f(x * 1.4426950408889634f);
}
__device__ __forceinline__ float sigf(float x) {
    return __builtin_amdgcn_rcpf(1.0f + fexp(-x));
}
__device__ __forceinline__ float tanhf_fast(float x) {
    return 1.0f - 2.0f * __builtin_amdgcn_rcpf(1.0f + fexp(2.0f * x));
}
__device__ __forceinline__ unsigned short f16bits(f16 x) {
    union { f16 h; unsigned short u; } v; v.h = x; return v.u;
}
__device__ __forceinline__ u32 packh2(float a, float b) {
    half2t hv; hv.x = (_Float16)a; hv.y = (_Float16)b;
    return __builtin_bit_cast(u32, hv);
}

#if __has_builtin(__builtin_amdgcn_fdot2)
__device__ __forceinline__ float dot2u(u32 a, u32 b, float c) {
    return __builtin_amdgcn_fdot2(__builtin_bit_cast(half2t, a),
                                  __builtin_bit_cast(half2t, b), c, false);
}
#else
__device__ __forceinline__ float dot2u(u32 a, u32 b, float c) {
    half2t x = __builtin_bit_cast(half2t, a), y = __builtin_bit_cast(half2t, b);
    return fmaf((float)x.y, (float)y.y, fmaf((float)x.x, (float)y.x, c));
}
#endif

// system-scope (sc0 sc1) plain ops: bypass L1/L2, serviced at the IC --
// coherent across XCDs without RMWs or fences.
__device__ __forceinline__ u64 sysload(const u64* p) {
    return __hip_atomic_load(p, __ATOMIC_RELAXED, __HIP_MEMORY_SCOPE_SYSTEM);
}
__device__ __forceinline__ void sysstore(u64* p, u64 v) {
    __hip_atomic_store(p, v, __ATOMIC_RELAXED, __HIP_MEMORY_SCOPE_SYSTEM);
}

// ---------- embedding gather ----------
__global__ void gather_k(const int* __restrict__ words, const int* __restrict__ tags,
                         const float* __restrict__ wemb, const float* __restrict__ temb,
                         float* __restrict__ x0) {
    int t = blockIdx.x;
    int w = words[t], g = tags[t];
    for (int c = threadIdx.x; c < H; c += 128) {
        float v = (c < WD) ? wemb[w * WD + c] : temb[g * TD + (c - WD)];
        x0[t * H + c] = v;
    }
}

// ---------- generic GEMM: out[t][r] = sum_k X[t*ldx+k]*W[r*ldw+wofs+k] + bias1[r]+bias2[r]
__global__ __launch_bounds__(256) void gemm_tn(
    const float* __restrict__ X, int ldx,
    const float* __restrict__ Wt, int ldw, int wofs,
    const float* __restrict__ bias1, const float* __restrict__ bias2,
    float* __restrict__ out, int ldo, int Rt, int K) {
    __shared__ float Xs[64][17];
    __shared__ float Ws[64][17];
    const int tid = threadIdx.x;
    const int t0 = blockIdx.x * 64, r0 = blockIdx.y * 64;
    const int lr = tid >> 2, kq = (tid & 3) * 4;
    const int ti = tid >> 4, rj = tid & 15;
    float acc[4][4] = {};
    for (int k0 = 0; k0 < K; k0 += 16) {
        float4 xv = *(const float4*)(X + (size_t)(t0 + lr) * ldx + k0 + kq);
        Xs[lr][kq + 0] = xv.x; Xs[lr][kq + 1] = xv.y;
        Xs[lr][kq + 2] = xv.z; Xs[lr][kq + 3] = xv.w;
        int r = r0 + lr;
        float4 wv = make_float4(0.f, 0.f, 0.f, 0.f);
        if (r < Rt) wv = *(const float4*)(Wt + (size_t)r * ldw + wofs + k0 + kq);
        Ws[lr][kq + 0] = wv.x; Ws[lr][kq + 1] = wv.y;
        Ws[lr][kq + 2] = wv.z; Ws[lr][kq + 3] = wv.w;
        __syncthreads();
#pragma unroll
        for (int k = 0; k < 16; k++) {
            float xr[4], wr[4];
#pragma unroll
            for (int m = 0; m < 4; m++) xr[m] = Xs[ti * 4 + m][k];
#pragma unroll
            for (int n = 0; n < 4; n++) wr[n] = Ws[rj * 4 + n][k];
#pragma unroll
            for (int m = 0; m < 4; m++)
#pragma unroll
                for (int n = 0; n < 4; n++)
                    acc[m][n] = fmaf(xr[m], wr[n], acc[m][n]);
        }
        __syncthreads();
    }
    int rq = r0 + rj * 4;
    if (rq < Rt) {
        float b[4];
#pragma unroll
        for (int n = 0; n < 4; n++) {
            int r = rq + n;
            b[n] = (bias1 ? bias1[r] : 0.f) + (bias2 ? bias2[r] : 0.f);
        }
#pragma unroll
        for (int m = 0; m < 4; m++) {
            int t = t0 + ti * 4 + m;
            float4 o;
            o.x = acc[m][0] + b[0]; o.y = acc[m][1] + b[1];
            o.z = acc[m][2] + b[2]; o.w = acc[m][3] + b[3];
            *(float4*)(out + (size_t)t * ldo + rq) = o;
        }
    }
}

// ---------- init: tagged words, contiguous [dir][parity][NPAIR] ----------
__global__ void lstm_init5(const float* __restrict__ h0, u64* sA, u64* sB) {
    int tid = threadIdx.x;
    const int TOT = 2 * 2 * NPAIR;
    for (int i = tid; i < TOT; i += 256) { sA[i] = 0xFFFFULL; sB[i] = 0xFFFFULL; }
    __syncthreads();
    for (int p = tid; p < 2 * NPAIR; p += 256) {
        int d = p / NPAIR, pr = p - d * NPAIR;
        size_t off = (size_t)(d * 2 + 0) * NPAIR + pr;   // parity 0, tag 0
        f16 a0 = (f16)h0[d * H + 2 * pr], b0 = (f16)h0[d * H + 2 * pr + 1];
        sA[off] = 0ULL | ((u64)f16bits(a0) << 16) | ((u64)f16bits(b0) << 32);
        f16 a1 = (f16)h0[2 * H + d * H + 2 * pr], b1 = (f16)h0[2 * H + d * H + 2 * pr + 1];
        sB[off] = 0ULL | ((u64)f16bits(a1) << 16) | ((u64)f16bits(b1) << 32);
    }
}

// ---------- persistent LSTM layer v6: full-k gate-rows, no shuffles ----------
// grid = 10 blocks (dir = b/5, blk = b%5), 512 threads.
// Block owns h rows [blk*80,+80). Workers tid<320: one full gate-row each
// (g = tid/80, r = tid%80), k=400 entirely in this thread -> 200 v_dot2,
// ZERO cross-lane reduction. h_s read from LDS as broadcast b128 (all lanes
// same address). tid in [320,480): pollers for the 160 foreign tagged words
// (R5 sc0/sc1 mechanism). tid in [480,512): G stagers. tid<80 does gate math;
// tid<40 publishes.
__global__ __launch_bounds__(512, 2) void lstm_layer6(
    const float* __restrict__ G,     // [2][T][G4] gate inputs, biases folded
    const float* __restrict__ Whh,   // [2][G4][H]
    const float* __restrict__ c0l,   // [2][H] this layer
    float* __restrict__ xout,        // [T][2H]
    u64* __restrict__ slots) {       // [2][2][NPAIR]
    const int role = blockIdx.x;
    const int dir = role / NBLK_D, blk = role - dir * NBLK_D;
    const int tid = threadIdx.x;
    const float* Wd = Whh + (size_t)dir * G4 * H;
    const float* Gd = G + (size_t)dir * T * G4;
    u64* sd = slots + (size_t)dir * 2 * NPAIR;

    __shared__ __align__(16) u32 hsh[NPAIR];   // h_s as 200 packed half2
    __shared__ float gsum[320];                // per-gate-row matvec sums
    __shared__ float gsh[2][320];              // staged G, double-buffered
    __shared__ f16 hpub[80];

    f16* hsh16 = (f16*)hsh;

    // ---- per-thread role setup ----
    const bool worker = tid < 320;
    const int g = tid / 80;            // gate (workers only)
    const int r = tid - g * 80;        // local row (workers only)

    // worker: load one full gate-row of Whh into 200 packed-half2 VGPRs
    u32 w[200];
    if (worker) {
        const float4* row = (const float4*)(Wd + (size_t)(g * H + blk * 80 + r) * H);
#pragma unroll
        for (int i = 0; i < 100; ++i) {
            float4 f = row[i];
            w[2 * i]     = packh2(f.x, f.y);
            w[2 * i + 1] = packh2(f.z, f.w);
        }
    }
    float c = (tid < 80) ? c0l[dir * H + blk * 80 + tid] : 0.f;

    // pre-loop: stagers stage G(0); tid<40 loads own h0 words into LDS
    if (tid >= 480) {
        int tt0 = dir ? (T - 1) : 0;
        for (int i = tid - 480; i < 320; i += 32) {
            int gg = i / 80, rr = i - gg * 80;
            gsh[0][i] = Gd[(size_t)tt0 * G4 + gg * H + blk * 80 + rr];
        }
    } else if (tid < 40) {
        u64 v = sysload(sd + blk * 40 + tid);      // parity 0, tag 0
        hsh[blk * 40 + tid] = (u32)(v >> 16);
    }

#pragma clang loop unroll(disable)
    for (int s = 0; s < T; ++s) {
        if (tid >= 320) {
            if (tid < 480) {
                // poller: one foreign word (parity s&1, tag s)
                int f = tid - 320;
                int widx = f + (f >= blk * 40 ? 40 : 0);
                u64* src = sd + (size_t)(s & 1) * NPAIR + widx;
                u64 v = sysload(src);
                int spins = 0;
                while ((unsigned)(v & 0xFFFFULL) != (unsigned)s) {
                    if (++spins > 16384) {
                        v = __hip_atomic_fetch_add(src, 0ULL, __ATOMIC_RELAXED,
                                                   __HIP_MEMORY_SCOPE_AGENT);
                    } else {
                        v = sysload(src);
                    }
                }
                hsh[widx] = (u32)(v >> 16);
            } else {
                // stager: G(s+1) into the other parity half
                int sn = (s + 1 < T) ? (s + 1) : s;
                int tt = dir ? (T - 1 - sn) : sn;
                for (int i = tid - 480; i < 320; i += 32) {
                    int gg = i / 80, rr = i - gg * 80;
                    gsh[(s + 1) & 1][i] = Gd[(size_t)tt * G4 + gg * H + blk * 80 + rr];
                }
            }
        }
        __syncthreads();   // (A) h_s complete in LDS

        if (worker) {
            const uint4* hp = (const uint4*)hsh;   // broadcast b128 reads
            float a = 0.f;
#pragma unroll
            for (int i = 0; i < 50; ++i) {
                uint4 q = hp[i];
                a = dot2u(w[4 * i + 0], q.x, a);
                a = dot2u(w[4 * i + 1], q.y, a);
                a = dot2u(w[4 * i + 2], q.z, a);
                a = dot2u(w[4 * i + 3], q.w, a);
            }
            gsum[tid] = a;
        }
        __syncthreads();   // (B) sums ready; all done reading hsh

        const int tt = dir ? (T - 1 - s) : s;
        if (tid < 80) {
            const float* gc = gsh[s & 1];
            float iv = gsum[tid]        + gc[tid];
            float fv = gsum[80 + tid]   + gc[80 + tid];
            float gv = gsum[160 + tid]  + gc[160 + tid];
            float ov = gsum[240 + tid]  + gc[240 + tid];
            float cn = sigf(fv) * c + sigf(iv) * tanhf_fast(gv);
            c = cn;
            float hn = sigf(ov) * tanhf_fast(cn);
            f16 hf = (f16)hn;
            hpub[tid] = hf;
            hsh16[blk * 80 + tid] = hf;    // own slice of h_{s+1}, LDS fast-path
            xout[(size_t)tt * (2 * H) + dir * H + blk * 80 + tid] = hn;
        }
        __syncthreads();   // (C) hpub/own-h ready

        if (tid < 40) {
            u32 pk = (u32)f16bits(hpub[2 * tid]) | ((u32)f16bits(hpub[2 * tid + 1]) << 16);
            sysstore(sd + (size_t)((s + 1) & 1) * NPAIR + blk * 40 + tid,
                     (u64)(unsigned)(s + 1) | ((u64)pk << 16));
        }
    }
}

// ---------- fused pairwise scorer ----------
__global__ __launch_bounds__(256) void scores_k(
    const float* __restrict__ pi, const float* __restrict__ pj,
    const float* __restrict__ w2, const float* __restrict__ b2p,
    float* __restrict__ out) {
    __shared__ float Ps[16][401];
    __shared__ float Qs[16][401];
    __shared__ float w2s[400];
    const int tid = threadIdx.x;
    const int i0 = blockIdx.y * 16, j0 = blockIdx.x * 16;
    for (int r = 0; r < 16; r++) {
        for (int k = tid; k < MLP_H; k += 256) {
            Ps[r][k] = pi[(size_t)(i0 + r) * MLP_H + k];
            Qs[r][k] = pj[(size_t)(j0 + r) * MLP_H + k];
        }
    }
    for (int k = tid; k < MLP_H; k += 256) w2s[k] = w2[k];
    __syncthreads();
    const int ti = tid >> 4, tj = tid & 15;
    float acc = 0.f;
#pragma unroll 4
    for (int k = 0; k < MLP_H; k++) {
        float x = Ps[ti][k] + Qs[tj][k];
        acc = fmaf(w2s[k], tanhf_fast(x), acc);
    }
    const int i = i0 + ti, j = j0 + tj;
    out[(size_t)i * T + j] = (i == j) ? 0.f : (acc + b2p[0]);
}

extern "C" void kernel_launch(void* const* d_in, const int* in_sizes, int n_in,
                              void* d_out, int out_size, void* d_ws, size_t ws_size,
                              hipStream_t stream) {
    const int*   words = (const int*)d_in[0];
    const int*   tags  = (const int*)d_in[1];
    const float* wemb  = (const float*)d_in[2];
    const float* temb  = (const float*)d_in[3];
    const float* Wih0  = (const float*)d_in[4];
    const float* Whh0  = (const float*)d_in[5];
    const float* bih0  = (const float*)d_in[6];
    const float* bhh0  = (const float*)d_in[7];
    const float* Wih1  = (const float*)d_in[8];
    const float* Whh1  = (const float*)d_in[9];
    const float* bih1  = (const float*)d_in[10];
    const float* bhh1  = (const float*)d_in[11];
    const float* W1    = (const float*)d_in[12];
    const float* b1    = (const float*)d_in[13];
    const float* W2    = (const float*)d_in[14];
    const float* b2    = (const float*)d_in[15];
    const float* h0    = (const float*)d_in[16];
    const float* c0    = (const float*)d_in[17];
    float* out = (float*)d_out;

    float* W = (float*)d_ws;
    float* x0   = W;                 // 256*400 (dead after layer-0 GEMMs)
    float* x1   = W + 102400;        // 256*800
    float* hvec = W + 307200;        // 256*800
    float* Gb   = W + 512000;        // 2*256*1600 (reused for both layers)
    float* pi   = W + 1331200;       // 256*400
    float* pj   = W + 1433600;       // 256*400
    // word arrays overlap x0's region (x0 dead before lstm_init5 runs)
    u64* slotsA = (u64*)W;                               // 800 u64
    u64* slotsB = (u64*)(W + 2048);                      // 800 u64

    // 1. embedding gather
    gather_k<<<T, 128, 0, stream>>>(words, tags, wemb, temb, x0);

    // 2. layer-0 gate inputs
    for (int d = 0; d < 2; d++) {
        gemm_tn<<<dim3(4, 25), 256, 0, stream>>>(
            x0, H, Wih0 + (size_t)d * G4 * H, H, 0,
            bih0 + d * G4, bhh0 + d * G4,
            Gb + (size_t)d * T * G4, G4, G4, H);
    }
    // 3. init tagged words (x0 now dead), then LSTM layer 0
    lstm_init5<<<1, 256, 0, stream>>>(h0, slotsA, slotsB);
    lstm_layer6<<<2 * NBLK_D, 512, 0, stream>>>(Gb, Whh0, c0, x1, slotsA);

    // 4. layer-1 gate inputs (K=800)
    for (int d = 0; d < 2; d++) {
        gemm_tn<<<dim3(4, 25), 256, 0, stream>>>(
            x1, 2 * H, Wih1 + (size_t)d * G4 * (2 * H), 2 * H, 0,
            bih1 + d * G4, bhh1 + d * G4,
            Gb + (size_t)d * T * G4, G4, G4, 2 * H);
    }
    // 5. LSTM layer 1
    lstm_layer6<<<2 * NBLK_D, 512, 0, stream>>>(Gb, Whh1, c0 + 2 * H, hvec, slotsB);

    // 6. pi = hvec @ W1a.T + b1 ; pj = hvec @ W1b.T
    gemm_tn<<<dim3(4, 7), 256, 0, stream>>>(
        hvec, 2 * H, W1, G4, 0, b1, nullptr, pi, MLP_H, MLP_H, 2 * H);
    gemm_tn<<<dim3(4, 7), 256, 0, stream>>>(
        hvec, 2 * H, W1, G4, 2 * H, nullptr, nullptr, pj, MLP_H, MLP_H, 2 * H);

    // 7. fused pairwise scores
    scores_k<<<dim3(16, 16), 256, 0, stream>>>(pi, pj, W2, b2, out);
}